// Round 5
// baseline (36.912 us; speedup 1.0000x reference)
//
#include <hip/hip_runtime.h>
#include <math.h>

#define N_ROWS   8192
#define DIM      128
#define NCLASS   100
#define EPS      1e-8f
#define CD       (NCLASS * DIM)          // 12800

// ws float layout: C[CD] | S[DIM] | nrm[N_ROWS]
#define S_OFF    CD
#define NRM_OFF  (CD + DIM)
#define ZERO_FLOATS (CD + DIM)           // C and S need zeroing each call

// K1: zero C, S, out.
__global__ void __launch_bounds__(256)
ntx_zero(float* __restrict__ ws, float* __restrict__ out) {
    int i = blockIdx.x * 256 + threadIdx.x;
    if (i < ZERO_FLOATS) ws[i] = 0.0f;
    if (i == 0) out[0] = 0.0f;
}

// K2: per-row normalize; class sums C (HW global fadd); total sum S; row norms.
// Wave handles a row PAIR: lanes 0-31 -> row 2rp, lanes 32-63 -> row 2rp+1.
__global__ void __launch_bounds__(256)
ntx_pass1(const float* __restrict__ z, const int* __restrict__ labels,
          float* __restrict__ C, float* __restrict__ S,
          float* __restrict__ nrmb)
{
    const int lane = threadIdx.x & 63;
    const int sub  = lane & 31;          // lane within half-wave
    const int half = lane >> 5;          // which row of the pair
    const int wid  = threadIdx.x >> 6;
    const int wave = (blockIdx.x * 256 + threadIdx.x) >> 6;
    const int nwave = gridDim.x * 4;

    float sx0 = 0, sx1 = 0, sx2 = 0, sx3 = 0;   // S partials for my 4 dims

    for (int rp = wave; rp < N_ROWS / 2; rp += nwave) {
        int row = 2 * rp + half;
        float4 v = *(const float4*)(z + (size_t)row * DIM + sub * 4);
        float ss = v.x * v.x + v.y * v.y + v.z * v.z + v.w * v.w;
        #pragma unroll
        for (int off = 1; off < 32; off <<= 1) ss += __shfl_xor(ss, off);
        float nrm = sqrtf(ss);
        float inv = 1.0f / fmaxf(nrm, EPS);
        if (sub == 0) nrmb[row] = nrm;
        int lbl = labels[row];
        float* dst = C + (size_t)lbl * DIM + sub * 4;
        float a = v.x * inv, b = v.y * inv, c = v.z * inv, d = v.w * inv;
        unsafeAtomicAdd(dst + 0, a);
        unsafeAtomicAdd(dst + 1, b);
        unsafeAtomicAdd(dst + 2, c);
        unsafeAtomicAdd(dst + 3, d);
        sx0 += a; sx1 += b; sx2 += c; sx3 += d;
    }

    // lanes l and l+32 own the same dims for different rows -> combine halves
    sx0 += __shfl_xor(sx0, 32);
    sx1 += __shfl_xor(sx1, 32);
    sx2 += __shfl_xor(sx2, 32);
    sx3 += __shfl_xor(sx3, 32);

    __shared__ float Sb[4 * DIM];
    if (half == 0) {
        float4 t = make_float4(sx0, sx1, sx2, sx3);
        *(float4*)(Sb + wid * DIM + sub * 4) = t;
    }
    __syncthreads();
    if (threadIdx.x < DIM) {
        float s = Sb[threadIdx.x] + Sb[DIM + threadIdx.x]
                + Sb[2 * DIM + threadIdx.x] + Sb[3 * DIM + threadIdx.x];
        unsafeAtomicAdd(&S[threadIdx.x], s);
    }
}

// K3: loss_i = -log((z_i.C[l_i] - ||z_i||) / (z_i.S)); mean into out.
__global__ void __launch_bounds__(256)
ntx_pass2(const float* __restrict__ z, const int* __restrict__ labels,
          const float* __restrict__ C, const float* __restrict__ S,
          const float* __restrict__ nrmb, float* __restrict__ out)
{
    const int lane = threadIdx.x & 63;
    const int sub  = lane & 31;
    const int half = lane >> 5;
    const int wid  = threadIdx.x >> 6;
    const int wave = (blockIdx.x * 256 + threadIdx.x) >> 6;
    const int nwave = gridDim.x * 4;

    float4 s4 = *(const float4*)(S + sub * 4);

    float lacc = 0.0f;
    for (int rp = wave; rp < N_ROWS / 2; rp += nwave) {
        int row = 2 * rp + half;
        float4 v  = *(const float4*)(z + (size_t)row * DIM + sub * 4);
        int lbl   = labels[row];
        float4 c4 = *(const float4*)(C + (size_t)lbl * DIM + sub * 4);
        float dc = v.x * c4.x + v.y * c4.y + v.z * c4.z + v.w * c4.w;
        float dt = v.x * s4.x + v.y * s4.y + v.z * s4.z + v.w * s4.w;
        #pragma unroll
        for (int off = 1; off < 32; off <<= 1) {
            dc += __shfl_xor(dc, off);
            dt += __shfl_xor(dt, off);
        }
        float nrm = nrmb[row];                  // broadcast within half-wave
        lacc += -logf((dc - nrm) / dt);         // 1/TEMP cancels in ratio
    }

    // halves hold different rows' losses; combine
    lacc += __shfl_xor(lacc, 32);
    __shared__ float wacc[4];
    if (lane == 0) wacc[wid] = lacc;
    __syncthreads();
    if (threadIdx.x == 0) {
        float b = wacc[0] + wacc[1] + wacc[2] + wacc[3];
        unsafeAtomicAdd(out, b * (1.0f / (float)N_ROWS));
    }
}

extern "C" void kernel_launch(void* const* d_in, const int* in_sizes, int n_in,
                              void* d_out, int out_size, void* d_ws, size_t ws_size,
                              hipStream_t stream) {
    const float* z      = (const float*)d_in[0];
    const int*   labels = (const int*)d_in[1];
    float* out = (float*)d_out;
    float* ws  = (float*)d_ws;
    float* C   = ws;
    float* S   = ws + S_OFF;
    float* nrm = ws + NRM_OFF;

    (void)in_sizes; (void)n_in; (void)out_size; (void)ws_size;

    ntx_zero <<<(ZERO_FLOATS + 255) / 256, 256, 0, stream>>>(ws, out);
    ntx_pass1<<<256, 256, 0, stream>>>(z, labels, C, S, nrm);
    ntx_pass2<<<256, 256, 0, stream>>>(z, labels, C, S, nrm, out);
}

// Round 6
// 25.201 us; speedup vs baseline: 1.4647x; 1.4647x over previous
//
#include <hip/hip_runtime.h>
#include <math.h>

#define N_ROWS   8192
#define DIM      128
#define NCLASS   100
#define EPS      1e-8f
#define CD       (NCLASS * DIM)        // 12800

// ws float layout: C[CD] | inv[N_ROWS]
#define INV_OFF  CD

// ---------------------------------------------------------------------------
// K1: zero C + out, and compute per-row inverse norms (one row per wave).
// grid = 2048 blocks * 256 thr = 8192 waves = 8192 rows.
__global__ void __launch_bounds__(256)
k1_prep(const float* __restrict__ z, float* __restrict__ C,
        float* __restrict__ invb, float* __restrict__ out)
{
    const int tid  = blockIdx.x * 256 + threadIdx.x;
    if (tid < CD) C[tid] = 0.0f;
    if (tid == 0) out[0] = 0.0f;

    const int row  = tid >> 6;                 // == global wave id
    const int lane = threadIdx.x & 63;
    float2 v = ((const float2*)(z + (size_t)row * DIM))[lane];
    float ss = v.x * v.x + v.y * v.y;
    #pragma unroll
    for (int off = 1; off < 64; off <<= 1) ss += __shfl_xor(ss, off);
    if (lane == 0) invb[row] = 1.0f / fmaxf(sqrtf(ss), EPS);
}

// ---------------------------------------------------------------------------
// K2: class-major C build, no per-row atomics.
// grid = 200 blocks: block handles class c = bid>>1 over rows [half*4096, +4096).
// Each wave scans labels via int4 + ballot; matched rows are loaded wave-wide
// (float2/lane) and accumulated in registers scaled by inv[row].
__global__ void __launch_bounds__(256)
k2_class_sums(const float* __restrict__ z, const int* __restrict__ labels,
              const float* __restrict__ invb, float* __restrict__ C)
{
    const int c    = blockIdx.x >> 1;
    const int half = blockIdx.x & 1;
    const int lane = threadIdx.x & 63;
    const int wid  = threadIdx.x >> 6;

    float ax = 0.0f, ay = 0.0f;

    const int lo = half * 4096;
    // each wave covers windows of 256 labels: wave wid starts at lo + wid*256,
    // strides by 1024; 4 iterations cover this block's 4096 labels.
    for (int base = lo + wid * 256; base < lo + 4096; base += 1024) {
        int4 l4 = ((const int4*)(labels + base))[lane];
        #pragma unroll
        for (int k = 0; k < 4; ++k) {
            int lbl = (k == 0) ? l4.x : (k == 1) ? l4.y : (k == 2) ? l4.z : l4.w;
            unsigned long long m = __ballot(lbl == c);
            while (m) {
                int j0 = __ffsll((long long)m) - 1; m &= m - 1;
                int j1 = -1;
                if (m) { j1 = __ffsll((long long)m) - 1; m &= m - 1; }
                int r0 = base + 4 * j0 + k;
                float2 v0 = ((const float2*)(z + (size_t)r0 * DIM))[lane];
                float iv0 = invb[r0];
                if (j1 >= 0) {
                    int r1 = base + 4 * j1 + k;
                    float2 v1 = ((const float2*)(z + (size_t)r1 * DIM))[lane];
                    float iv1 = invb[r1];
                    ax += v0.x * iv0; ay += v0.y * iv0;
                    ax += v1.x * iv1; ay += v1.y * iv1;
                } else {
                    ax += v0.x * iv0; ay += v0.y * iv0;
                }
            }
        }
    }

    __shared__ float Cb[4][DIM];
    ((float2*)Cb[wid])[lane] = make_float2(ax, ay);
    __syncthreads();
    if (threadIdx.x < DIM) {
        float s = Cb[0][threadIdx.x] + Cb[1][threadIdx.x]
                + Cb[2][threadIdx.x] + Cb[3][threadIdx.x];
        // two blocks per class -> atomic combine (C pre-zeroed in K1)
        unsafeAtomicAdd(&C[(size_t)c * DIM + threadIdx.x], s);
    }
}

// ---------------------------------------------------------------------------
// K3: per-block S = sum_c C[c] in LDS, then per-row loss.
// grid = 512 blocks = 2048 waves; wave handles row-pairs {w, w+2048} (half-wave
// float4 scheme: lanes 0-31 -> row 2rp, lanes 32-63 -> row 2rp+1).
__global__ void __launch_bounds__(256)
k3_loss(const float* __restrict__ z, const int* __restrict__ labels,
        const float* __restrict__ C, const float* __restrict__ invb,
        float* __restrict__ out)
{
    __shared__ float Sp[2 * DIM];
    {
        int d = threadIdx.x & (DIM - 1);
        int h = threadIdx.x >> 7;
        float s = 0.0f;
        for (int c = h * 50; c < h * 50 + 50; ++c) s += C[c * DIM + d];
        Sp[h * DIM + d] = s;
    }
    __syncthreads();
    if (threadIdx.x < DIM) Sp[threadIdx.x] += Sp[DIM + threadIdx.x];
    __syncthreads();

    const int lane = threadIdx.x & 63;
    const int sub  = lane & 31;
    const int half = lane >> 5;
    const int wid  = threadIdx.x >> 6;
    const int w    = blockIdx.x * 4 + wid;          // 0..2047

    float4 s4 = *(const float4*)(Sp + sub * 4);

    float lacc = 0.0f;
    #pragma unroll
    for (int k = 0; k < 2; ++k) {
        int rp  = w + k * 2048;
        int row = 2 * rp + half;
        float4 v  = *(const float4*)(z + (size_t)row * DIM + sub * 4);
        int lbl   = labels[row];
        float4 c4 = *(const float4*)(C + (size_t)lbl * DIM + sub * 4);
        float dc = v.x * c4.x + v.y * c4.y + v.z * c4.z + v.w * c4.w;
        float dt = v.x * s4.x + v.y * s4.y + v.z * s4.z + v.w * s4.w;
        #pragma unroll
        for (int off = 1; off < 32; off <<= 1) {
            dc += __shfl_xor(dc, off);
            dt += __shfl_xor(dt, off);
        }
        float iv = invb[row];
        lacc += -logf((dc * iv - 1.0f) / (dt * iv));  // 1/TEMP cancels
    }

    lacc += __shfl_xor(lacc, 32);
    __shared__ float wacc[4];
    if (lane == 0) wacc[wid] = lacc;
    __syncthreads();
    if (threadIdx.x == 0) {
        float b = wacc[0] + wacc[1] + wacc[2] + wacc[3];
        unsafeAtomicAdd(out, b * (1.0f / (float)N_ROWS));
    }
}

extern "C" void kernel_launch(void* const* d_in, const int* in_sizes, int n_in,
                              void* d_out, int out_size, void* d_ws, size_t ws_size,
                              hipStream_t stream) {
    const float* z      = (const float*)d_in[0];
    const int*   labels = (const int*)d_in[1];
    float* out  = (float*)d_out;
    float* ws   = (float*)d_ws;
    float* C    = ws;
    float* invb = ws + INV_OFF;

    (void)in_sizes; (void)n_in; (void)out_size; (void)ws_size;

    k1_prep      <<<2048, 256, 0, stream>>>(z, C, invb, out);
    k2_class_sums<<<200,  256, 0, stream>>>(z, labels, invb, C);
    k3_loss      <<<512,  256, 0, stream>>>(z, labels, C, invb, out);
}

// Round 7
// 22.143 us; speedup vs baseline: 1.6670x; 1.1381x over previous
//
#include <hip/hip_runtime.h>
#include <math.h>

#define N_ROWS 8192
#define DIM    128
#define NCLASS 100
#define CD     (NCLASS * DIM)       // 12800 floats in ws: C only

// ---------------------------------------------------------------------------
// KA: one block per class c. 16 waves scan 512 labels each (ballot+rank into a
// per-wave LDS list), then process matched rows in 4-deep load batches.
// Writes C[c][0..127] non-atomically (no zero pass needed). Block 0 zeroes out.
__global__ void __launch_bounds__(1024)
ka_class_sums(const float* __restrict__ z, const int* __restrict__ labels,
              float* __restrict__ C, float* __restrict__ out)
{
    __shared__ int   lists[16][64];
    __shared__ float Cb[16][DIM];

    const int c    = blockIdx.x;
    const int lane = threadIdx.x & 63;
    const int wid  = threadIdx.x >> 6;      // 0..15
    const int base = wid * 512;             // this wave's label window

    if (c == 0 && threadIdx.x == 0) out[0] = 0.0f;

    // ---- scan: 512 labels = 2 x int4 per lane; ballot + rank -> LDS list ----
    int cnt = 0;
    #pragma unroll
    for (int it = 0; it < 2; ++it) {
        int b4 = base + it * 256;
        int4 l4 = ((const int4*)(labels + b4))[lane];
        #pragma unroll
        for (int k = 0; k < 4; ++k) {
            int lbl = (k == 0) ? l4.x : (k == 1) ? l4.y : (k == 2) ? l4.z : l4.w;
            bool hit = (lbl == c);
            unsigned long long m = __ballot(hit);
            if (hit) {
                int rank = __popcll(m & ((1ull << lane) - 1ull));
                lists[wid][cnt + rank] = b4 + 4 * lane + k;
            }
            cnt += __popcll(m);
        }
    }

    // ---- process matched rows, 4 at a time (loads issued before chains) ----
    float ax = 0.0f, ay = 0.0f;
    for (int i = 0; i < cnt; i += 4) {
        int k  = cnt - i;
        int r0 = lists[wid][i];
        int r1 = lists[wid][(k > 1) ? i + 1 : i];
        int r2 = lists[wid][(k > 2) ? i + 2 : i];
        int r3 = lists[wid][(k > 3) ? i + 3 : i];
        float2 v0 = ((const float2*)(z + (size_t)r0 * DIM))[lane];
        float2 v1 = ((const float2*)(z + (size_t)r1 * DIM))[lane];
        float2 v2 = ((const float2*)(z + (size_t)r2 * DIM))[lane];
        float2 v3 = ((const float2*)(z + (size_t)r3 * DIM))[lane];
        float s0 = v0.x * v0.x + v0.y * v0.y;
        float s1 = v1.x * v1.x + v1.y * v1.y;
        float s2 = v2.x * v2.x + v2.y * v2.y;
        float s3 = v3.x * v3.x + v3.y * v3.y;
        #pragma unroll
        for (int off = 1; off < 64; off <<= 1) {
            s0 += __shfl_xor(s0, off);
            s1 += __shfl_xor(s1, off);
            s2 += __shfl_xor(s2, off);
            s3 += __shfl_xor(s3, off);
        }
        float i0 = rsqrtf(s0), i1 = rsqrtf(s1);
        float i2 = rsqrtf(s2), i3 = rsqrtf(s3);
        float w1 = (k > 1) ? 1.0f : 0.0f;
        float w2 = (k > 2) ? 1.0f : 0.0f;
        float w3 = (k > 3) ? 1.0f : 0.0f;
        ax += v0.x * i0 + w1 * (v1.x * i1) + w2 * (v2.x * i2) + w3 * (v3.x * i3);
        ay += v0.y * i0 + w1 * (v1.y * i1) + w2 * (v2.y * i2) + w3 * (v3.y * i3);
    }

    ((float2*)Cb[wid])[lane] = make_float2(ax, ay);
    __syncthreads();
    if (threadIdx.x < DIM) {
        float s = 0.0f;
        #pragma unroll
        for (int w = 0; w < 16; ++w) s += Cb[w][threadIdx.x];
        C[c * DIM + threadIdx.x] = s;
    }
}

// ---------------------------------------------------------------------------
// KB: per-block S = sum_c C[c] (L2-hot), then half-wave float4 row pairs:
// loss_i = -log((z.C[l] - ||z||) / (z.S)); one atomic per block into out.
__global__ void __launch_bounds__(256)
kb_loss(const float* __restrict__ z, const int* __restrict__ labels,
        const float* __restrict__ C, float* __restrict__ out)
{
    __shared__ float Sp[2][DIM];
    {
        int d = threadIdx.x & (DIM - 1);
        int h = threadIdx.x >> 7;
        float s = 0.0f;
        #pragma unroll 5
        for (int j = 0; j < 50; ++j) s += C[(h * 50 + j) * DIM + d];
        Sp[h][d] = s;
    }
    __syncthreads();
    if (threadIdx.x < DIM) Sp[0][threadIdx.x] += Sp[1][threadIdx.x];
    __syncthreads();

    const int lane = threadIdx.x & 63;
    const int sub  = lane & 31;
    const int half = lane >> 5;
    const int wid  = threadIdx.x >> 6;
    const int w    = blockIdx.x * 4 + wid;     // 0..2047

    float4 s4 = *(const float4*)(&Sp[0][sub * 4]);

    float lacc = 0.0f;
    #pragma unroll
    for (int i = 0; i < 2; ++i) {
        int p   = w + i * 2048;                // pair id, 0..4095
        int row = 2 * p + half;
        float4 v  = *(const float4*)(z + (size_t)row * DIM + sub * 4);
        int lbl   = labels[row];
        float4 c4 = *(const float4*)(C + (size_t)lbl * DIM + sub * 4);
        float dc = v.x * c4.x + v.y * c4.y + v.z * c4.z + v.w * c4.w;
        float dt = v.x * s4.x + v.y * s4.y + v.z * s4.z + v.w * s4.w;
        float ss = v.x * v.x + v.y * v.y + v.z * v.z + v.w * v.w;
        #pragma unroll
        for (int off = 1; off < 32; off <<= 1) {
            dc += __shfl_xor(dc, off);
            dt += __shfl_xor(dt, off);
            ss += __shfl_xor(ss, off);
        }
        float inv = rsqrtf(ss);
        float nrm = ss * inv;                  // ||z_i||
        lacc += -__logf((dc - nrm) / dt);      // 1/TEMP cancels in the ratio
    }

    lacc += __shfl_xor(lacc, 32);
    __shared__ float wacc[4];
    if (lane == 0) wacc[wid] = lacc;
    __syncthreads();
    if (threadIdx.x == 0)
        unsafeAtomicAdd(out, (wacc[0] + wacc[1] + wacc[2] + wacc[3])
                             * (1.0f / (float)N_ROWS));
}

extern "C" void kernel_launch(void* const* d_in, const int* in_sizes, int n_in,
                              void* d_out, int out_size, void* d_ws, size_t ws_size,
                              hipStream_t stream) {
    const float* z      = (const float*)d_in[0];
    const int*   labels = (const int*)d_in[1];
    float* out = (float*)d_out;
    float* C   = (float*)d_ws;

    (void)in_sizes; (void)n_in; (void)out_size; (void)ws_size;

    ka_class_sums<<<NCLASS, 1024, 0, stream>>>(z, labels, C, out);
    kb_loss      <<<512,    256,  0, stream>>>(z, labels, C, out);
}

// Round 8
// 18.677 us; speedup vs baseline: 1.9763x; 1.1856x over previous
//
#include <hip/hip_runtime.h>
#include <math.h>

#define N_ROWS 8192
#define DIM    128
#define NCLASS 100
#define CD     (NCLASS * DIM)       // C: 12800 floats

// ws float layout: C[CD] | invb[N_ROWS]
#define INV_OFF CD

// ---------------------------------------------------------------------------
// KA: one block per class c. 16 waves scan 512 labels each (ballot+rank list),
// then process matched rows HALF-WAVE (float4/lane, 5-step shuffles), 4 rows
// per batch (2 paired loads). Stores inv-norms. Non-atomic C write.
__global__ void __launch_bounds__(1024)
ka_class_sums(const float* __restrict__ z, const int* __restrict__ labels,
              float* __restrict__ C, float* __restrict__ invb,
              float* __restrict__ out)
{
    __shared__ int    lists[16][64];
    __shared__ float4 Cb[16][2][32];

    const int c    = blockIdx.x;
    const int lane = threadIdx.x & 63;
    const int sub  = lane & 31;
    const int half = lane >> 5;
    const int wid  = threadIdx.x >> 6;      // 0..15
    const int base = wid * 512;

    if (c == 0 && threadIdx.x == 0) out[0] = 0.0f;

    // ---- scan 512 labels: 2 x int4 per lane; ballot + rank -> list ----
    int cnt = 0;
    #pragma unroll
    for (int it = 0; it < 2; ++it) {
        int b4 = base + it * 256;
        int4 l4 = ((const int4*)(labels + b4))[lane];
        #pragma unroll
        for (int k = 0; k < 4; ++k) {
            int lbl = (k == 0) ? l4.x : (k == 1) ? l4.y : (k == 2) ? l4.z : l4.w;
            bool hit = (lbl == c);
            unsigned long long m = __ballot(hit);
            if (hit) {
                int rank = __popcll(m & ((1ull << lane) - 1ull));
                lists[wid][cnt + rank] = b4 + 4 * lane + k;
            }
            cnt += __popcll(m);
        }
    }

    // ---- process rows 4 at a time: halves own rows (i+half), (i+2+half) ----
    float4 acc = make_float4(0.0f, 0.0f, 0.0f, 0.0f);
    for (int i = 0; i < cnt; i += 4) {
        int iA = i + half, iB = i + 2 + half;
        float wA = (iA < cnt) ? 1.0f : 0.0f;
        float wB = (iB < cnt) ? 1.0f : 0.0f;
        int rA = lists[wid][(iA < cnt) ? iA : i];
        int rB = lists[wid][(iB < cnt) ? iB : i];
        float4 vA = *(const float4*)(z + (size_t)rA * DIM + sub * 4);
        float4 vB = *(const float4*)(z + (size_t)rB * DIM + sub * 4);
        float sA = vA.x * vA.x + vA.y * vA.y + vA.z * vA.z + vA.w * vA.w;
        float sB = vB.x * vB.x + vB.y * vB.y + vB.z * vB.z + vB.w * vB.w;
        #pragma unroll
        for (int off = 1; off < 32; off <<= 1) {
            sA += __shfl_xor(sA, off);
            sB += __shfl_xor(sB, off);
        }
        float ivA = rsqrtf(sA), ivB = rsqrtf(sB);
        if (sub == 0) {
            if (wA != 0.0f) invb[rA] = ivA;
            if (wB != 0.0f) invb[rB] = ivB;
        }
        float fA = wA * ivA, fB = wB * ivB;
        acc.x += vA.x * fA + vB.x * fB;
        acc.y += vA.y * fA + vB.y * fB;
        acc.z += vA.z * fA + vB.z * fB;
        acc.w += vA.w * fA + vB.w * fB;
    }

    Cb[wid][half][sub] = acc;
    __syncthreads();

    // ---- reduce 32 partials per dim; write C[c] ----
    if (threadIdx.x < DIM) {
        int g = threadIdx.x >> 2, comp = threadIdx.x & 3;
        const float* Cf = (const float*)Cb;       // [32][32][4] flat
        float s = 0.0f;
        #pragma unroll
        for (int w = 0; w < 32; ++w) s += Cf[(w * 32 + g) * 4 + comp];
        C[c * DIM + threadIdx.x] = s;
    }
}

// ---------------------------------------------------------------------------
// KB: all-thread float4 S-scan, then half-wave float4 row loss:
// loss_i = -log((z.C[l]*iv - 1) / (z.S*iv)); one atomic per block.
__global__ void __launch_bounds__(256)
kb_loss(const float* __restrict__ z, const int* __restrict__ labels,
        const float* __restrict__ C, const float* __restrict__ invb,
        float* __restrict__ out)
{
    __shared__ float4 Sp[8][32];
    __shared__ float4 S4s[32];
    {
        int g = threadIdx.x & 31, chunk = threadIdx.x >> 5;
        float4 s = make_float4(0.0f, 0.0f, 0.0f, 0.0f);
        for (int cc = chunk; cc < NCLASS; cc += 8) {
            float4 v = *(const float4*)(C + cc * DIM + g * 4);
            s.x += v.x; s.y += v.y; s.z += v.z; s.w += v.w;
        }
        Sp[chunk][g] = s;
    }
    __syncthreads();
    if (threadIdx.x < 32) {
        float4 s = make_float4(0.0f, 0.0f, 0.0f, 0.0f);
        #pragma unroll
        for (int ch = 0; ch < 8; ++ch) {
            float4 v = Sp[ch][threadIdx.x];
            s.x += v.x; s.y += v.y; s.z += v.z; s.w += v.w;
        }
        S4s[threadIdx.x] = s;
    }
    __syncthreads();

    const int lane = threadIdx.x & 63;
    const int sub  = lane & 31;
    const int half = lane >> 5;
    const int wid  = threadIdx.x >> 6;
    const int hw   = (blockIdx.x * 4 + wid) * 2 + half;   // 0..2047

    float4 s4 = S4s[sub];

    float lacc = 0.0f;
    #pragma unroll
    for (int i = 0; i < 4; ++i) {
        int row = hw + i * 2048;
        float4 v  = *(const float4*)(z + (size_t)row * DIM + sub * 4);
        int lbl   = labels[row];
        float4 c4 = *(const float4*)(C + (size_t)lbl * DIM + sub * 4);
        float iv  = invb[row];
        float dc = v.x * c4.x + v.y * c4.y + v.z * c4.z + v.w * c4.w;
        float dt = v.x * s4.x + v.y * s4.y + v.z * s4.z + v.w * s4.w;
        #pragma unroll
        for (int off = 1; off < 32; off <<= 1) {
            dc += __shfl_xor(dc, off);
            dt += __shfl_xor(dt, off);
        }
        lacc += -__logf((dc * iv - 1.0f) / (dt * iv));  // 1/TEMP cancels
    }

    lacc += __shfl_xor(lacc, 32);
    __shared__ float wacc[4];
    if (lane == 0) wacc[wid] = lacc;
    __syncthreads();
    if (threadIdx.x == 0)
        unsafeAtomicAdd(out, (wacc[0] + wacc[1] + wacc[2] + wacc[3])
                             * (1.0f / (float)N_ROWS));
}

extern "C" void kernel_launch(void* const* d_in, const int* in_sizes, int n_in,
                              void* d_out, int out_size, void* d_ws, size_t ws_size,
                              hipStream_t stream) {
    const float* z      = (const float*)d_in[0];
    const int*   labels = (const int*)d_in[1];
    float* out  = (float*)d_out;
    float* ws   = (float*)d_ws;
    float* C    = ws;
    float* invb = ws + INV_OFF;

    (void)in_sizes; (void)n_in; (void)out_size; (void)ws_size;

    ka_class_sums<<<NCLASS, 1024, 0, stream>>>(z, labels, C, invb, out);
    kb_loss      <<<256,    256,  0, stream>>>(z, labels, C, invb, out);
}

// Round 9
// 16.835 us; speedup vs baseline: 2.1926x; 1.1094x over previous
//
#include <hip/hip_runtime.h>
#include <math.h>

#define N_ROWS 8192
#define DIM    128
#define NCLASS 100
#define CD     (NCLASS * DIM)       // C: 12800 floats

// ws float layout: C[CD] | invb[N_ROWS]
#define INV_OFF CD

// ---------------------------------------------------------------------------
// KA: one block per class c. 16 waves scan 512 labels each (ballot+rank list),
// then process matched rows in ONE batch of 8 (half-wave float4, 4 rows per
// half, interleaved shuffle chains). Stores inv-norms. Non-atomic C write.
__global__ void __launch_bounds__(1024)
ka_class_sums(const float* __restrict__ z, const int* __restrict__ labels,
              float* __restrict__ C, float* __restrict__ invb,
              float* __restrict__ out)
{
    __shared__ int    lists[16][64];
    __shared__ float4 Cb[16][2][32];

    const int c    = blockIdx.x;
    const int lane = threadIdx.x & 63;
    const int sub  = lane & 31;
    const int half = lane >> 5;
    const int wid  = threadIdx.x >> 6;      // 0..15
    const int base = wid * 512;

    if (c == 0 && threadIdx.x == 0) out[0] = 0.0f;

    // ---- scan 512 labels: 2 x int4 per lane; ballot + rank -> list ----
    int cnt = 0;
    #pragma unroll
    for (int it = 0; it < 2; ++it) {
        int b4 = base + it * 256;
        int4 l4 = ((const int4*)(labels + b4))[lane];
        #pragma unroll
        for (int k = 0; k < 4; ++k) {
            int lbl = (k == 0) ? l4.x : (k == 1) ? l4.y : (k == 2) ? l4.z : l4.w;
            bool hit = (lbl == c);
            unsigned long long m = __ballot(hit);
            if (hit) {
                int rank = __popcll(m & ((1ull << lane) - 1ull));
                lists[wid][cnt + rank] = b4 + 4 * lane + k;
            }
            cnt += __popcll(m);
        }
    }

    // ---- process rows 8 at a time: half h owns rows i+2k+h, k=0..3 ----
    float4 acc = make_float4(0.0f, 0.0f, 0.0f, 0.0f);
    for (int i = 0; i < cnt; i += 8) {
        int i0 = i + half, i1 = i + 2 + half, i2 = i + 4 + half, i3 = i + 6 + half;
        float w0 = (i0 < cnt) ? 1.0f : 0.0f;
        float w1 = (i1 < cnt) ? 1.0f : 0.0f;
        float w2 = (i2 < cnt) ? 1.0f : 0.0f;
        float w3 = (i3 < cnt) ? 1.0f : 0.0f;
        int r0 = lists[wid][(i0 < cnt) ? i0 : 0];
        int r1 = lists[wid][(i1 < cnt) ? i1 : 0];
        int r2 = lists[wid][(i2 < cnt) ? i2 : 0];
        int r3 = lists[wid][(i3 < cnt) ? i3 : 0];
        float4 v0 = *(const float4*)(z + (size_t)r0 * DIM + sub * 4);
        float4 v1 = *(const float4*)(z + (size_t)r1 * DIM + sub * 4);
        float4 v2 = *(const float4*)(z + (size_t)r2 * DIM + sub * 4);
        float4 v3 = *(const float4*)(z + (size_t)r3 * DIM + sub * 4);
        float s0 = v0.x * v0.x + v0.y * v0.y + v0.z * v0.z + v0.w * v0.w;
        float s1 = v1.x * v1.x + v1.y * v1.y + v1.z * v1.z + v1.w * v1.w;
        float s2 = v2.x * v2.x + v2.y * v2.y + v2.z * v2.z + v2.w * v2.w;
        float s3 = v3.x * v3.x + v3.y * v3.y + v3.z * v3.z + v3.w * v3.w;
        #pragma unroll
        for (int off = 1; off < 32; off <<= 1) {
            s0 += __shfl_xor(s0, off);
            s1 += __shfl_xor(s1, off);
            s2 += __shfl_xor(s2, off);
            s3 += __shfl_xor(s3, off);
        }
        float iv0 = rsqrtf(s0), iv1 = rsqrtf(s1);
        float iv2 = rsqrtf(s2), iv3 = rsqrtf(s3);
        if (sub == 0) {
            if (w0 != 0.0f) invb[r0] = iv0;
            if (w1 != 0.0f) invb[r1] = iv1;
            if (w2 != 0.0f) invb[r2] = iv2;
            if (w3 != 0.0f) invb[r3] = iv3;
        }
        float f0 = w0 * iv0, f1 = w1 * iv1, f2 = w2 * iv2, f3 = w3 * iv3;
        acc.x += v0.x * f0 + v1.x * f1 + v2.x * f2 + v3.x * f3;
        acc.y += v0.y * f0 + v1.y * f1 + v2.y * f2 + v3.y * f3;
        acc.z += v0.z * f0 + v1.z * f1 + v2.z * f2 + v3.z * f3;
        acc.w += v0.w * f0 + v1.w * f1 + v2.w * f2 + v3.w * f3;
    }

    Cb[wid][half][sub] = acc;
    __syncthreads();

    // ---- reduce 32 half-wave partials per dim; write C[c] ----
    if (threadIdx.x < DIM) {
        int g = threadIdx.x >> 2, comp = threadIdx.x & 3;
        const float* Cf = (const float*)Cb;       // [32][32][4] flat
        float s = 0.0f;
        #pragma unroll
        for (int w = 0; w < 32; ++w) s += Cf[(w * 32 + g) * 4 + comp];
        C[c * DIM + threadIdx.x] = s;
    }
}

// ---------------------------------------------------------------------------
// KB: 512-thread blocks (2 waves/SIMD). Prefetch z/labels/inv into registers
// BEFORE the S-scan so HBM latency hides under it, then per-row loss.
__global__ void __launch_bounds__(512)
kb_loss(const float* __restrict__ z, const int* __restrict__ labels,
        const float* __restrict__ C, const float* __restrict__ invb,
        float* __restrict__ out)
{
    const int tid  = threadIdx.x;
    const int lane = tid & 63;
    const int sub  = lane & 31;
    const int half = lane >> 5;
    const int wid  = tid >> 6;                       // 0..7
    const int hw   = (blockIdx.x * 8 + wid) * 2 + half;  // 0..4095

    const int rowA = hw, rowB = hw + 4096;

    // ---- issue-early: row data into registers before the S-scan ----
    float4 vA = *(const float4*)(z + (size_t)rowA * DIM + sub * 4);
    float4 vB = *(const float4*)(z + (size_t)rowB * DIM + sub * 4);
    int   lA = labels[rowA], lB = labels[rowB];
    float iA = invb[rowA],   iB = invb[rowB];

    // ---- S-scan: 16 chunks x 32 dim-groups ----
    __shared__ float4 Sp[16][32];
    __shared__ float4 S4s[32];
    {
        int g = tid & 31, chunk = tid >> 5;
        float4 s = make_float4(0.0f, 0.0f, 0.0f, 0.0f);
        for (int cc = chunk; cc < NCLASS; cc += 16) {
            float4 v = *(const float4*)(C + cc * DIM + g * 4);
            s.x += v.x; s.y += v.y; s.z += v.z; s.w += v.w;
        }
        Sp[chunk][g] = s;
    }
    __syncthreads();
    if (tid < 32) {
        float4 s = make_float4(0.0f, 0.0f, 0.0f, 0.0f);
        #pragma unroll
        for (int ch = 0; ch < 16; ++ch) {
            float4 v = Sp[ch][tid];
            s.x += v.x; s.y += v.y; s.z += v.z; s.w += v.w;
        }
        S4s[tid] = s;
    }
    __syncthreads();

    float4 s4 = S4s[sub];
    float4 cA = *(const float4*)(C + (size_t)lA * DIM + sub * 4);
    float4 cB = *(const float4*)(C + (size_t)lB * DIM + sub * 4);

    float dcA = vA.x * cA.x + vA.y * cA.y + vA.z * cA.z + vA.w * cA.w;
    float dtA = vA.x * s4.x + vA.y * s4.y + vA.z * s4.z + vA.w * s4.w;
    float dcB = vB.x * cB.x + vB.y * cB.y + vB.z * cB.z + vB.w * cB.w;
    float dtB = vB.x * s4.x + vB.y * s4.y + vB.z * s4.z + vB.w * s4.w;
    #pragma unroll
    for (int off = 1; off < 32; off <<= 1) {
        dcA += __shfl_xor(dcA, off);
        dtA += __shfl_xor(dtA, off);
        dcB += __shfl_xor(dcB, off);
        dtB += __shfl_xor(dtB, off);
    }
    float lacc = -__logf((dcA * iA - 1.0f) / (dtA * iA))
                 -__logf((dcB * iB - 1.0f) / (dtB * iB));

    lacc += __shfl_xor(lacc, 32);
    __shared__ float wacc[8];
    if (lane == 0) wacc[wid] = lacc;
    __syncthreads();
    if (tid == 0) {
        float b = wacc[0] + wacc[1] + wacc[2] + wacc[3]
                + wacc[4] + wacc[5] + wacc[6] + wacc[7];
        unsafeAtomicAdd(out, b * (1.0f / (float)N_ROWS));
    }
}

extern "C" void kernel_launch(void* const* d_in, const int* in_sizes, int n_in,
                              void* d_out, int out_size, void* d_ws, size_t ws_size,
                              hipStream_t stream) {
    const float* z      = (const float*)d_in[0];
    const int*   labels = (const int*)d_in[1];
    float* out  = (float*)d_out;
    float* ws   = (float*)d_ws;
    float* C    = ws;
    float* invb = ws + INV_OFF;

    (void)in_sizes; (void)n_in; (void)out_size; (void)ws_size;

    ka_class_sums<<<NCLASS, 1024, 0, stream>>>(z, labels, C, invb, out);
    kb_loss      <<<256,    512,  0, stream>>>(z, labels, C, invb, out);
}